// Round 18
// baseline (74.474 us; speedup 1.0000x reference)
//
#include <hip/hip_runtime.h>

// ECConv: out = relu(concat(nf[:8192], mean_seg(relu(EF@We+be).reshape(E,64,64) @ h_src)) @ Wn + bn)
// Sizes: E=65536, N_SRC=32768, N_DST=8192, EDGE_IN=32, NODE_IN=64, HIDDEN=64
// R18: FINAL TRIM. R17 banked bf16-m (total 73.5->70.4). Edge = 43.4us issue-mix equilibrium
//      (invariant to occupancy/LDS-work/packing/sourcing/pipelining across R6-R16). This
//      round: final7 = 16 rows/block (512 blocks, halves Wn restage traffic) + 4 rows/wave
//      gather+fma ILP. Edge/prep/scan/fill byte-identical to R17 proven.
// Lessons: R2 fp32 atomics memory-side. R4 serial scan 20us. R5/R9 spills (WRITE>>payload).
//      R6 sequential dispatches don't stack. R10 loads never the binder. R11 ablation: LDS
//      21us + epilogue hazard ~25us. R12 compiler collapses source SWP. R13 unexplained
//      nondeterminism = revert. R15 pipeline +2.5us. R16 total-LDS halving null. R17 bf16-m
//      free (absmax unchanged).

typedef float f32x4 __attribute__((ext_vector_type(4)));
typedef float f32x2 __attribute__((ext_vector_type(2)));
typedef __bf16 bf16x8 __attribute__((ext_vector_type(8)));
typedef __bf16 bf16x4 __attribute__((ext_vector_type(4)));

#define E_TOT   65536
#define NDST    8192
#define EPW     72    // bf16 hs pad (atomic-fallback kernel)
#define EPF     68    // f32 hs pad (fast kernel)

// ---- prep: pack We (fp32 [32][4096]) -> MFMA-B fragment order bf16 + bias tiles; zero cnt ----
// Tile T = d0*4 + ht covers GEMM cols n = (ht*16 + c)*64 + d0, c=0..15.
// B frag for mfma_f32_16x16x32_bf16: lane l holds B[k=(l>>4)*8+j][col=l&15], j=0..7.
__global__ __launch_bounds__(256) void prep_kernel(
    const float* __restrict__ We, const float* __restrict__ be,
    __bf16* __restrict__ Wp, float* __restrict__ bp, int* __restrict__ cnt_i) {
  int tid = blockIdx.x * 256 + threadIdx.x;       // 16384 packers
  if (tid < NDST) cnt_i[tid] = 0;                 // zero histogram (hist runs in edge dispatch)
  int T = tid >> 6, l = tid & 63;
  int d0 = T >> 2, ht = T & 3;
  int c = l & 15, kg = l >> 4;
  int ncol = (ht * 16 + c) * 64 + d0;
  bf16x8 v;
#pragma unroll
  for (int j = 0; j < 8; ++j) v[j] = (__bf16)We[(kg * 8 + j) * 4096 + ncol];
  *reinterpret_cast<bf16x8*>(Wp + tid * 8) = v;
  if (l < 16) bp[T * 16 + l] = be[(ht * 16 + l) * 64 + d0];
}

// ---- parallel exclusive scan over 8192 bins (one block, shfl + LDS) ----
__global__ __launch_bounds__(256) void scan_kernel(const int* __restrict__ cnt_i,
                                                   int* __restrict__ off,
                                                   int* __restrict__ cursor) {
  __shared__ int wsum[4];
  const int t = threadIdx.x;
  const int lane = t & 63, w = t >> 6;
  int vals[32];
  const int4* cp = (const int4*)(cnt_i + t * 32);
#pragma unroll
  for (int i = 0; i < 8; ++i) {
    int4 v = cp[i];
    vals[i * 4 + 0] = v.x; vals[i * 4 + 1] = v.y;
    vals[i * 4 + 2] = v.z; vals[i * 4 + 3] = v.w;
  }
  int loc[32];
  int s = 0;
#pragma unroll
  for (int i = 0; i < 32; ++i) { loc[i] = s; s += vals[i]; }
  int inc = s;
#pragma unroll
  for (int d = 1; d < 64; d <<= 1) {
    int n = __shfl_up(inc, d, 64);
    if (lane >= d) inc += n;
  }
  if (lane == 63) wsum[w] = inc;
  __syncthreads();
  int base = inc - s;
#pragma unroll
  for (int i = 0; i < 4; ++i)
    if (i < w) base += wsum[i];
#pragma unroll
  for (int i = 0; i < 32; ++i) {
    int v = base + loc[i];
    off[t * 32 + i] = v;
    cursor[t * 32 + i] = v;
  }
  if (t == 255) off[8192] = E_TOT;
}

// ---- fill: scatter edge ids into CSR order (int atomics on cursor) ----
__global__ void fill_kernel(const int* __restrict__ dst, int* __restrict__ cursor,
                            int* __restrict__ eid) {
  int e = blockIdx.x * 256 + threadIdx.x;
  int slot = atomicAdd(&cursor[dst[e]], 1);
  eid[slot] = e;
}

// ---- edge compute (2-ht waves, enforced pipeline): m[e][h] = sum_d relu(ef@We+be)*h_src ----
// Block: 128 threads = 2 waves, 64 edges; wave w owns ht {2w, 2w+1}. m stored bf16.
__global__ __launch_bounds__(128, 2) void edge12_kernel(
    const float* __restrict__ nf, const float* __restrict__ ef,
    const int* __restrict__ src, const int* __restrict__ dst,
    const __bf16* __restrict__ Wp, const float* __restrict__ bp,
    __bf16* __restrict__ m, int* __restrict__ cnt_i) {
  __shared__ float hs[64 * EPF];   // transposed f32 h_src: hs[d][e_local], 17.4 KB
  const int t = threadIdx.x;
  const int eblk = blockIdx.x << 6;

  // stage h_src transposed: thread t -> edge el=t&63, d-half q=t>>6 (32 d each)
  {
    const int el = t & 63, q = t >> 6;
    const int srow = src[eblk + el];
    const f32x4* nfr = (const f32x4*)(nf + (srow << 6) + (q << 5));
#pragma unroll
    for (int i = 0; i < 8; ++i) {
      f32x4 v = nfr[i];
      const int dbase = (q << 5) + i * 4;
      hs[(dbase + 0) * EPF + el] = v[0];
      hs[(dbase + 1) * EPF + el] = v[1];
      hs[(dbase + 2) * EPF + el] = v[2];
      hs[(dbase + 3) * EPF + el] = v[3];
    }
  }

  // fused dst histogram (cnt_i zeroed by prep)
  if (t < 64) atomicAdd(&cnt_i[dst[eblk + t]], 1);

  const int w = t >> 6, l = t & 63;
  const int c = l & 15, g = l >> 4;
  const int ht0 = (w << 1), ht1 = (w << 1) + 1;   // this wave's two h-quadrants

  // A fragments: lane holds A[row=c][k=g*8+j] for 4 edge-groups of 16
  bf16x8 afr[4];
#pragma unroll
  for (int as = 0; as < 4; ++as) {
    const int e = eblk + as * 16 + c;
    const f32x4* p = (const f32x4*)(ef + (e << 5) + (g << 3));
    f32x4 v0 = p[0], v1 = p[1];
    bf16x8 a;
    a[0] = (__bf16)v0[0]; a[1] = (__bf16)v0[1]; a[2] = (__bf16)v0[2]; a[3] = (__bf16)v0[3];
    a[4] = (__bf16)v1[0]; a[5] = (__bf16)v1[1]; a[6] = (__bf16)v1[2]; a[7] = (__bf16)v1[3];
    afr[as] = a;
  }

  f32x2 accA0[4], accB0[4], accA1[4], accB1[4];   // [as]; ht0 / ht1
#pragma unroll
  for (int i = 0; i < 4; ++i) {
    accA0[i][0]=0.f; accA0[i][1]=0.f; accB0[i][0]=0.f; accB0[i][1]=0.f;
    accA1[i][0]=0.f; accA1[i][1]=0.f; accB1[i][0]=0.f; accB1[i][1]=0.f;
  }

  const bf16x8* WpV = (const bf16x8*)Wp;

  // B/bias depth-2 prefetch regs (per ht)
  bf16x8 bfE0 = WpV[(0 * 4 + ht0) * 64 + l];
  bf16x8 bfE1 = WpV[(0 * 4 + ht1) * 64 + l];
  float  bvE0 = bp[(0 * 4 + ht0) * 16 + c];
  float  bvE1 = bp[(0 * 4 + ht1) * 16 + c];
  bf16x8 bfO0 = WpV[(1 * 4 + ht0) * 64 + l];
  bf16x8 bfO1 = WpV[(1 * 4 + ht1) * 64 + l];
  float  bvO0 = bp[(1 * 4 + ht0) * 16 + c];
  float  bvO1 = bp[(1 * 4 + ht1) * 16 + c];

  __syncthreads();   // hs ready

  const int hoff = g << 2;

  // pipeline register sets: tmp (E/O parity x ht x as), hv (E/O, h-invariant)
  f32x4 tEA0, tEA1, tEA2, tEA3, tEB0, tEB1, tEB2, tEB3;
  f32x4 tOA0, tOA1, tOA2, tOA3, tOB0, tOB1, tOB2, tOB3;
  f32x4 hE0, hE1, hE2, hE3, hO0, hO1, hO2, hO3;

#define ISSUE_SET2(TA0, TA1, TA2, TA3, TB0, TB1, TB2, TB3, BF0, BV0, BF1, BV1)     \
  {                                                                                \
    const f32x4 cb0 = {BV0, BV0, BV0, BV0};                                        \
    const f32x4 cb1 = {BV1, BV1, BV1, BV1};                                        \
    TA0 = __builtin_amdgcn_mfma_f32_16x16x32_bf16(afr[0], BF0, cb0, 0, 0, 0);      \
    TA1 = __builtin_amdgcn_mfma_f32_16x16x32_bf16(afr[1], BF0, cb0, 0, 0, 0);      \
    TA2 = __builtin_amdgcn_mfma_f32_16x16x32_bf16(afr[2], BF0, cb0, 0, 0, 0);      \
    TA3 = __builtin_amdgcn_mfma_f32_16x16x32_bf16(afr[3], BF0, cb0, 0, 0, 0);      \
    TB0 = __builtin_amdgcn_mfma_f32_16x16x32_bf16(afr[0], BF1, cb1, 0, 0, 0);      \
    TB1 = __builtin_amdgcn_mfma_f32_16x16x32_bf16(afr[1], BF1, cb1, 0, 0, 0);      \
    TB2 = __builtin_amdgcn_mfma_f32_16x16x32_bf16(afr[2], BF1, cb1, 0, 0, 0);      \
    TB3 = __builtin_amdgcn_mfma_f32_16x16x32_bf16(afr[3], BF1, cb1, 0, 0, 0);      \
    asm volatile("" : "+v"(TA0), "+v"(TA1), "+v"(TA2), "+v"(TA3),                  \
                      "+v"(TB0), "+v"(TB1), "+v"(TB2), "+v"(TB3));                 \
  }

#define LOADHV_SET(H0, H1, H2, H3, D0)                                             \
  {                                                                                \
    H0 = *(const f32x4*)&hs[(D0) * EPF +  0 + hoff];                               \
    H1 = *(const f32x4*)&hs[(D0) * EPF + 16 + hoff];                               \
    H2 = *(const f32x4*)&hs[(D0) * EPF + 32 + hoff];                               \
    H3 = *(const f32x4*)&hs[(D0) * EPF + 48 + hoff];                               \
  }

#define CONSUME_ONE2(ACCA, ACCB, AS, TT, HH)                                       \
  {                                                                                \
    f32x2 p, hl, hh;                                                               \
    hl = __builtin_shufflevector(HH, HH, 0, 1);                                    \
    hh = __builtin_shufflevector(HH, HH, 2, 3);                                    \
    p[0] = fmaxf(TT[0], 0.f); p[1] = fmaxf(TT[1], 0.f);                            \
    asm volatile("v_pk_fma_f32 %0, %1, %2, %0" : "+v"(ACCA[AS]) : "v"(p), "v"(hl));\
    p[0] = fmaxf(TT[2], 0.f); p[1] = fmaxf(TT[3], 0.f);                            \
    asm volatile("v_pk_fma_f32 %0, %1, %2, %0" : "+v"(ACCB[AS]) : "v"(p), "v"(hh));\
  }

#define CONSUME_BOTH(TA0, TA1, TA2, TA3, TB0, TB1, TB2, TB3, H0, H1, H2, H3)       \
  CONSUME_ONE2(accA0, accB0, 0, TA0, H0) CONSUME_ONE2(accA0, accB0, 1, TA1, H1)    \
  CONSUME_ONE2(accA0, accB0, 2, TA2, H2) CONSUME_ONE2(accA0, accB0, 3, TA3, H3)    \
  CONSUME_ONE2(accA1, accB1, 0, TB0, H0) CONSUME_ONE2(accA1, accB1, 1, TB1, H1)    \
  CONSUME_ONE2(accA1, accB1, 2, TB2, H2) CONSUME_ONE2(accA1, accB1, 3, TB3, H3)

  // prologue: issue sections d0=0 (E) and d0=1 (O)
  ISSUE_SET2(tEA0, tEA1, tEA2, tEA3, tEB0, tEB1, tEB2, tEB3, bfE0, bvE0, bfE1, bvE1)
  LOADHV_SET(hE0, hE1, hE2, hE3, 0)
  bfE0 = WpV[(2 * 4 + ht0) * 64 + l];  bvE0 = bp[(2 * 4 + ht0) * 16 + c];
  bfE1 = WpV[(2 * 4 + ht1) * 64 + l];  bvE1 = bp[(2 * 4 + ht1) * 16 + c];
  ISSUE_SET2(tOA0, tOA1, tOA2, tOA3, tOB0, tOB1, tOB2, tOB3, bfO0, bvO0, bfO1, bvO1)
  LOADHV_SET(hO0, hO1, hO2, hO3, 1)
  bfO0 = WpV[(3 * 4 + ht0) * 64 + l];  bvO0 = bp[(3 * 4 + ht0) * 16 + c];
  bfO1 = WpV[(3 * 4 + ht1) * 64 + l];  bvO1 = bp[(3 * 4 + ht1) * 16 + c];

#pragma unroll 2
  for (int d0 = 2; d0 < 64; d0 += 2) {
    // consume E (d0-2), reissue E (d0)
    CONSUME_BOTH(tEA0, tEA1, tEA2, tEA3, tEB0, tEB1, tEB2, tEB3, hE0, hE1, hE2, hE3)
    ISSUE_SET2(tEA0, tEA1, tEA2, tEA3, tEB0, tEB1, tEB2, tEB3, bfE0, bvE0, bfE1, bvE1)
    LOADHV_SET(hE0, hE1, hE2, hE3, d0)
    if (d0 + 2 < 64) {
      bfE0 = WpV[((d0 + 2) * 4 + ht0) * 64 + l];  bvE0 = bp[((d0 + 2) * 4 + ht0) * 16 + c];
      bfE1 = WpV[((d0 + 2) * 4 + ht1) * 64 + l];  bvE1 = bp[((d0 + 2) * 4 + ht1) * 16 + c];
    }
    // consume O (d0-1), reissue O (d0+1)
    CONSUME_BOTH(tOA0, tOA1, tOA2, tOA3, tOB0, tOB1, tOB2, tOB3, hO0, hO1, hO2, hO3)
    ISSUE_SET2(tOA0, tOA1, tOA2, tOA3, tOB0, tOB1, tOB2, tOB3, bfO0, bvO0, bfO1, bvO1)
    LOADHV_SET(hO0, hO1, hO2, hO3, d0 + 1)
    if (d0 + 3 < 64) {
      bfO0 = WpV[((d0 + 3) * 4 + ht0) * 64 + l];  bvO0 = bp[((d0 + 3) * 4 + ht0) * 16 + c];
      bfO1 = WpV[((d0 + 3) * 4 + ht1) * 64 + l];  bvO1 = bp[((d0 + 3) * 4 + ht1) * 16 + c];
    }
  }

  // epilogue: consume last two sections (d0=62 E, d0=63 O)
  CONSUME_BOTH(tEA0, tEA1, tEA2, tEA3, tEB0, tEB1, tEB2, tEB3, hE0, hE1, hE2, hE3)
  CONSUME_BOTH(tOA0, tOA1, tOA2, tOA3, tOB0, tOB1, tOB2, tOB3, hO0, hO1, hO2, hO3)

#undef ISSUE_SET2
#undef LOADHV_SET
#undef CONSUME_ONE2
#undef CONSUME_BOTH

  // stores (bf16): per (ht, as, row): 16 lanes x 2B = 32B segments
  const int hb0 = (ht0 << 4) + c;
  const int hb1 = (ht1 << 4) + c;
#pragma unroll
  for (int as = 0; as < 4; ++as) {
    const int ebase = eblk + as * 16 + (g << 2);
    m[((ebase + 0) << 6) + hb0] = (__bf16)accA0[as][0];
    m[((ebase + 1) << 6) + hb0] = (__bf16)accA0[as][1];
    m[((ebase + 2) << 6) + hb0] = (__bf16)accB0[as][0];
    m[((ebase + 3) << 6) + hb0] = (__bf16)accB0[as][1];
    m[((ebase + 0) << 6) + hb1] = (__bf16)accA1[as][0];
    m[((ebase + 1) << 6) + hb1] = (__bf16)accA1[as][1];
    m[((ebase + 2) << 6) + hb1] = (__bf16)accB1[as][0];
    m[((ebase + 3) << 6) + hb1] = (__bf16)accB1[as][1];
  }
}

// ---- final: gather-mean per dst (CSR, bf16 m) + relu(concat@Wn + bn); 16 rows/block ----
__global__ __launch_bounds__(256) void final7_kernel(
    const float* __restrict__ nf, const __bf16* __restrict__ m,
    const int* __restrict__ off, const int* __restrict__ eid,
    const float* __restrict__ Wn, const float* __restrict__ bn,
    float* __restrict__ out) {
  __shared__ float wn_s[128 * 64];   // 32 KB
  __shared__ float hn_s[16 * 64];    // 4 KB
  const int t = threadIdx.x;
#pragma unroll
  for (int i = 0; i < 8; ++i)
    ((f32x4*)wn_s)[i * 256 + t] = ((const f32x4*)Wn)[i * 256 + t];

  const int w = t >> 6, h = t & 63;
  const int row0 = blockIdx.x * 16 + w * 4;

#pragma unroll
  for (int i = 0; i < 4; ++i) {
    const int d = row0 + i;
    const int lo = off[d], hi = off[d + 1];
    float a0 = 0.f, a1 = 0.f, a2 = 0.f, a3 = 0.f;
    int j = lo;
    for (; j + 4 <= hi; j += 4) {
      const int e0 = eid[j], e1 = eid[j + 1], e2 = eid[j + 2], e3 = eid[j + 3];
      a0 += (float)m[(e0 << 6) + h];
      a1 += (float)m[(e1 << 6) + h];
      a2 += (float)m[(e2 << 6) + h];
      a3 += (float)m[(e3 << 6) + h];
    }
    for (; j < hi; ++j)
      a0 += (float)m[(eid[j] << 6) + h];
    const float a = (a0 + a1) + (a2 + a3);
    hn_s[(w * 4 + i) * 64 + h] = (hi > lo) ? a * (1.f / (float)(hi - lo)) : 0.f;
  }
  __syncthreads();

  const float bv = bn[h];
  float acc[4] = {bv, bv, bv, bv};
#pragma unroll 4
  for (int k = 0; k < 64; ++k) {
    const float wv = wn_s[k * 64 + h];
#pragma unroll
    for (int i = 0; i < 4; ++i)
      acc[i] = fmaf(nf[(row0 + i) * 64 + k], wv, acc[i]);
  }
#pragma unroll 4
  for (int k = 0; k < 64; ++k) {
    const float wv = wn_s[(64 + k) * 64 + h];
#pragma unroll
    for (int i = 0; i < 4; ++i)
      acc[i] = fmaf(hn_s[(w * 4 + i) * 64 + k], wv, acc[i]);
  }
#pragma unroll
  for (int i = 0; i < 4; ++i)
    out[(row0 + i) * 64 + h] = fmaxf(acc[i], 0.f);
}

// ================= atomic fallback (R3, proven) =================

__global__ __launch_bounds__(256, 4) void edge_kernel(
    const float* __restrict__ nf, const float* __restrict__ ef,
    const int* __restrict__ src, const int* __restrict__ dst,
    const __bf16* __restrict__ Wp, const float* __restrict__ bp,
    float* __restrict__ msum, float* __restrict__ cnt_g) {
  __shared__ __bf16 hs[64 * EPW];
  const int t = threadIdx.x;
  const int eblk = blockIdx.x << 6;
  {
    const int el = t & 63, q = t >> 6;
    const int srow = src[eblk + el];
    const f32x4* nfr = (const f32x4*)(nf + (srow << 6) + (q << 4));
#pragma unroll
    for (int i = 0; i < 4; ++i) {
      f32x4 v = nfr[i];
      const int dbase = (q << 4) + i * 4;
      hs[(dbase + 0) * EPW + el] = (__bf16)v[0];
      hs[(dbase + 1) * EPW + el] = (__bf16)v[1];
      hs[(dbase + 2) * EPW + el] = (__bf16)v[2];
      hs[(dbase + 3) * EPW + el] = (__bf16)v[3];
    }
  }
  const int w = t >> 6, l = t & 63, c = l & 15, g = l >> 4;
  bf16x8 afr[4];
#pragma unroll
  for (int as = 0; as < 4; ++as) {
    const int e = eblk + as * 16 + c;
    const f32x4* p = (const f32x4*)(ef + (e << 5) + (g << 3));
    f32x4 v0 = p[0], v1 = p[1];
    bf16x8 a;
    a[0] = (__bf16)v0[0]; a[1] = (__bf16)v0[1]; a[2] = (__bf16)v0[2]; a[3] = (__bf16)v0[3];
    a[4] = (__bf16)v1[0]; a[5] = (__bf16)v1[1]; a[6] = (__bf16)v1[2]; a[7] = (__bf16)v1[3];
    afr[as] = a;
  }
  __syncthreads();
  f32x4 acc[4];
#pragma unroll
  for (int i = 0; i < 4; ++i) { acc[i][0]=0.f; acc[i][1]=0.f; acc[i][2]=0.f; acc[i][3]=0.f; }
  const bf16x8* WpV = (const bf16x8*)Wp;
  const f32x4 zero = {0.f, 0.f, 0.f, 0.f};
#pragma unroll 4
  for (int d0 = 0; d0 < 64; ++d0) {
    const int T = d0 * 4 + w;
    const bf16x8 bfr = WpV[T * 64 + l];
    const float bv = bp[T * 16 + c];
    const f32x4 cb = {bv, bv, bv, bv};
#pragma unroll
    for (int as = 0; as < 4; ++as) {
      const bf16x4 hv = *(const bf16x4*)&hs[d0 * EPW + as * 16 + (g << 2)];
      const f32x4 hvf = {(float)hv[0], (float)hv[1], (float)hv[2], (float)hv[3]};
      f32x4 tmp = __builtin_amdgcn_mfma_f32_16x16x32_bf16(afr[as], bfr, cb, 0, 0, 0);
      tmp = __builtin_elementwise_max(tmp, zero);
      acc[as] = tmp * hvf + acc[as];
    }
  }
#pragma unroll
  for (int as = 0; as < 4; ++as)
#pragma unroll
    for (int r = 0; r < 4; ++r) {
      const int e = eblk + as * 16 + (g << 2) + r;
      const int dd = dst[e];
      unsafeAtomicAdd(msum + (dd << 6) + (w << 4) + c, acc[as][r]);
      if (w == 0 && c == 0) unsafeAtomicAdd(cnt_g + dd, 1.0f);
    }
}

__global__ __launch_bounds__(256) void final_kernel(
    const float* __restrict__ nf, const float* __restrict__ msum,
    const float* __restrict__ cnt, const float* __restrict__ Wn,
    const float* __restrict__ bn, float* __restrict__ out) {
  __shared__ float wn_s[128 * 64];
  const int t = threadIdx.x;
#pragma unroll
  for (int i = 0; i < 8; ++i)
    ((f32x4*)wn_s)[i * 256 + t] = ((const f32x4*)Wn)[i * 256 + t];
  __syncthreads();
  const int w = t >> 6, h = t & 63;
  const int row0 = blockIdx.x * 16 + w * 4;
  const float bv = bn[h];
  float acc[4] = {bv, bv, bv, bv};
  float s[4];
#pragma unroll
  for (int i = 0; i < 4; ++i) {
    const float cv = cnt[row0 + i];
    s[i] = cv > 0.f ? 1.f / cv : 0.f;
  }
#pragma unroll 4
  for (int k = 0; k < 64; ++k) {
    const float wv = wn_s[k * 64 + h];
#pragma unroll
    for (int i = 0; i < 4; ++i) acc[i] = fmaf(nf[(row0 + i) * 64 + k], wv, acc[i]);
  }
#pragma unroll 4
  for (int k = 0; k < 64; ++k) {
    const float wv = wn_s[(64 + k) * 64 + h];
#pragma unroll
    for (int i = 0; i < 4; ++i) acc[i] = fmaf(msum[(row0 + i) * 64 + k] * s[i], wv, acc[i]);
  }
#pragma unroll
  for (int i = 0; i < 4; ++i) out[(row0 + i) * 64 + h] = fmaxf(acc[i], 0.f);
}

// ================= launcher =================

extern "C" void kernel_launch(void* const* d_in, const int* in_sizes, int n_in,
                              void* d_out, int out_size, void* d_ws, size_t ws_size,
                              hipStream_t stream) {
  const float* nf  = (const float*)d_in[0];
  const float* ef  = (const float*)d_in[1];
  const int*   src = (const int*)d_in[2];
  const int*   dst = (const int*)d_in[3];
  const float* We  = (const float*)d_in[4];
  const float* be  = (const float*)d_in[5];
  const float* Wn  = (const float*)d_in[6];
  const float* bn  = (const float*)d_in[7];
  float* out = (float*)d_out;
  char* ws = (char*)d_ws;

  const size_t MB = 16777216;  // m region bytes (layout unchanged; bf16 m uses half)
  const size_t T_OFF    = MB;
  const size_t T_CURSOR = T_OFF + 36864;
  const size_t T_CNTI   = T_CURSOR + 32768;
  const size_t T_EID    = T_CNTI + 32768;
  const size_t T_WP     = T_EID + 262144;
  const size_t T_BP     = T_WP + 262144;
  const size_t NEED     = T_BP + 16384;      // ~17.4 MB

  if (ws_size >= NEED) {
    __bf16* m      = (__bf16*)ws;
    int*    off    = (int*)(ws + T_OFF);
    int*    cursor = (int*)(ws + T_CURSOR);
    int*    cnt_i  = (int*)(ws + T_CNTI);
    int*    eid    = (int*)(ws + T_EID);
    __bf16* Wp     = (__bf16*)(ws + T_WP);
    float*  bp     = (float*)(ws + T_BP);

    prep_kernel<<<64, 256, 0, stream>>>(We, be, Wp, bp, cnt_i);
    edge12_kernel<<<E_TOT / 64, 128, 0, stream>>>(nf, ef, src, dst, Wp, bp, m, cnt_i);
    scan_kernel<<<1, 256, 0, stream>>>(cnt_i, off, cursor);
    fill_kernel<<<E_TOT / 256, 256, 0, stream>>>(dst, cursor, eid);
    final7_kernel<<<NDST / 16, 256, 0, stream>>>(nf, m, off, eid, Wn, bn, out);
  } else {
    // atomic fallback
    float* msum = (float*)ws;
    float* cnt  = (float*)(ws + 2097152);
    const size_t need = 2097152 + 32768 + 262144 + 16384;
    __bf16* Wp;
    float*  bp;
    if (ws_size >= need) {
      Wp = (__bf16*)(ws + 2097152 + 32768);
      bp = (float*)(ws + 2097152 + 32768 + 262144);
    } else {
      Wp = (__bf16*)d_out;
      bp = (float*)((char*)d_out + 262144);
    }
    hipMemsetAsync(msum, 0, 2097152 + 32768, stream);
    prep_kernel<<<64, 256, 0, stream>>>(We, be, Wp, bp, (int*)cnt);
    edge_kernel<<<E_TOT / 64, 256, 0, stream>>>(nf, ef, src, dst, Wp, bp, msum, cnt);
    final_kernel<<<NDST / 16, 256, 0, stream>>>(nf, msum, cnt, Wn, bn, out);
  }
}

// Round 19
// 69.514 us; speedup vs baseline: 1.0714x; 1.0714x over previous
//
#include <hip/hip_runtime.h>

// ECConv: out = relu(concat(nf[:8192], mean_seg(relu(EF@We+be).reshape(E,64,64) @ h_src)) @ Wn + bn)
// Sizes: E=65536, N_SRC=32768, N_DST=8192, EDGE_IN=32, NODE_IN=64, HIDDEN=64
// R19: REVERT to R17 (best verified: 70.4us). R18's final7 (16 rows/block) regressed ~4us —
//      gather long-tail serialization per wave outweighed halved Wn restage traffic (which
//      was L2-resident and never the binder). Edge at 43.4us issue-mix equilibrium after 11
//      structural attacks (invariance matrix: occupancy/LDS-work/path/packing/sourcing/SWP
//      all null). This config = plateau candidate.
// Lessons: R2 fp32 atomics memory-side. R4 serial scan 20us. R5/R9 spills (WRITE>>payload).
//      R6 sequential dispatches don't stack. R10 loads never the binder. R11 ablation: LDS
//      21us + epilogue hazard ~25us. R12 compiler collapses source SWP. R13 unexplained
//      nondeterminism = revert. R15 pipeline +2.5us. R16 total-LDS halving null. R17 bf16-m
//      free. R18 final 16-rows/block regresses (gather tails).

typedef float f32x4 __attribute__((ext_vector_type(4)));
typedef float f32x2 __attribute__((ext_vector_type(2)));
typedef __bf16 bf16x8 __attribute__((ext_vector_type(8)));
typedef __bf16 bf16x4 __attribute__((ext_vector_type(4)));

#define E_TOT   65536
#define NDST    8192
#define EPW     72    // bf16 hs pad (atomic-fallback kernel)
#define EPF     68    // f32 hs pad (fast kernel)

// ---- prep: pack We (fp32 [32][4096]) -> MFMA-B fragment order bf16 + bias tiles; zero cnt ----
// Tile T = d0*4 + ht covers GEMM cols n = (ht*16 + c)*64 + d0, c=0..15.
// B frag for mfma_f32_16x16x32_bf16: lane l holds B[k=(l>>4)*8+j][col=l&15], j=0..7.
__global__ __launch_bounds__(256) void prep_kernel(
    const float* __restrict__ We, const float* __restrict__ be,
    __bf16* __restrict__ Wp, float* __restrict__ bp, int* __restrict__ cnt_i) {
  int tid = blockIdx.x * 256 + threadIdx.x;       // 16384 packers
  if (tid < NDST) cnt_i[tid] = 0;                 // zero histogram (hist runs in edge dispatch)
  int T = tid >> 6, l = tid & 63;
  int d0 = T >> 2, ht = T & 3;
  int c = l & 15, kg = l >> 4;
  int ncol = (ht * 16 + c) * 64 + d0;
  bf16x8 v;
#pragma unroll
  for (int j = 0; j < 8; ++j) v[j] = (__bf16)We[(kg * 8 + j) * 4096 + ncol];
  *reinterpret_cast<bf16x8*>(Wp + tid * 8) = v;
  if (l < 16) bp[T * 16 + l] = be[(ht * 16 + l) * 64 + d0];
}

// ---- parallel exclusive scan over 8192 bins (one block, shfl + LDS) ----
__global__ __launch_bounds__(256) void scan_kernel(const int* __restrict__ cnt_i,
                                                   int* __restrict__ off,
                                                   int* __restrict__ cursor) {
  __shared__ int wsum[4];
  const int t = threadIdx.x;
  const int lane = t & 63, w = t >> 6;
  int vals[32];
  const int4* cp = (const int4*)(cnt_i + t * 32);
#pragma unroll
  for (int i = 0; i < 8; ++i) {
    int4 v = cp[i];
    vals[i * 4 + 0] = v.x; vals[i * 4 + 1] = v.y;
    vals[i * 4 + 2] = v.z; vals[i * 4 + 3] = v.w;
  }
  int loc[32];
  int s = 0;
#pragma unroll
  for (int i = 0; i < 32; ++i) { loc[i] = s; s += vals[i]; }
  int inc = s;
#pragma unroll
  for (int d = 1; d < 64; d <<= 1) {
    int n = __shfl_up(inc, d, 64);
    if (lane >= d) inc += n;
  }
  if (lane == 63) wsum[w] = inc;
  __syncthreads();
  int base = inc - s;
#pragma unroll
  for (int i = 0; i < 4; ++i)
    if (i < w) base += wsum[i];
#pragma unroll
  for (int i = 0; i < 32; ++i) {
    int v = base + loc[i];
    off[t * 32 + i] = v;
    cursor[t * 32 + i] = v;
  }
  if (t == 255) off[8192] = E_TOT;
}

// ---- fill: scatter edge ids into CSR order (int atomics on cursor) ----
__global__ void fill_kernel(const int* __restrict__ dst, int* __restrict__ cursor,
                            int* __restrict__ eid) {
  int e = blockIdx.x * 256 + threadIdx.x;
  int slot = atomicAdd(&cursor[dst[e]], 1);
  eid[slot] = e;
}

// ---- edge compute (2-ht waves, enforced pipeline): m[e][h] = sum_d relu(ef@We+be)*h_src ----
// Block: 128 threads = 2 waves, 64 edges; wave w owns ht {2w, 2w+1}. m stored bf16.
__global__ __launch_bounds__(128, 2) void edge12_kernel(
    const float* __restrict__ nf, const float* __restrict__ ef,
    const int* __restrict__ src, const int* __restrict__ dst,
    const __bf16* __restrict__ Wp, const float* __restrict__ bp,
    __bf16* __restrict__ m, int* __restrict__ cnt_i) {
  __shared__ float hs[64 * EPF];   // transposed f32 h_src: hs[d][e_local], 17.4 KB
  const int t = threadIdx.x;
  const int eblk = blockIdx.x << 6;

  // stage h_src transposed: thread t -> edge el=t&63, d-half q=t>>6 (32 d each)
  {
    const int el = t & 63, q = t >> 6;
    const int srow = src[eblk + el];
    const f32x4* nfr = (const f32x4*)(nf + (srow << 6) + (q << 5));
#pragma unroll
    for (int i = 0; i < 8; ++i) {
      f32x4 v = nfr[i];
      const int dbase = (q << 5) + i * 4;
      hs[(dbase + 0) * EPF + el] = v[0];
      hs[(dbase + 1) * EPF + el] = v[1];
      hs[(dbase + 2) * EPF + el] = v[2];
      hs[(dbase + 3) * EPF + el] = v[3];
    }
  }

  // fused dst histogram (cnt_i zeroed by prep)
  if (t < 64) atomicAdd(&cnt_i[dst[eblk + t]], 1);

  const int w = t >> 6, l = t & 63;
  const int c = l & 15, g = l >> 4;
  const int ht0 = (w << 1), ht1 = (w << 1) + 1;   // this wave's two h-quadrants

  // A fragments: lane holds A[row=c][k=g*8+j] for 4 edge-groups of 16
  bf16x8 afr[4];
#pragma unroll
  for (int as = 0; as < 4; ++as) {
    const int e = eblk + as * 16 + c;
    const f32x4* p = (const f32x4*)(ef + (e << 5) + (g << 3));
    f32x4 v0 = p[0], v1 = p[1];
    bf16x8 a;
    a[0] = (__bf16)v0[0]; a[1] = (__bf16)v0[1]; a[2] = (__bf16)v0[2]; a[3] = (__bf16)v0[3];
    a[4] = (__bf16)v1[0]; a[5] = (__bf16)v1[1]; a[6] = (__bf16)v1[2]; a[7] = (__bf16)v1[3];
    afr[as] = a;
  }

  f32x2 accA0[4], accB0[4], accA1[4], accB1[4];   // [as]; ht0 / ht1
#pragma unroll
  for (int i = 0; i < 4; ++i) {
    accA0[i][0]=0.f; accA0[i][1]=0.f; accB0[i][0]=0.f; accB0[i][1]=0.f;
    accA1[i][0]=0.f; accA1[i][1]=0.f; accB1[i][0]=0.f; accB1[i][1]=0.f;
  }

  const bf16x8* WpV = (const bf16x8*)Wp;

  // B/bias depth-2 prefetch regs (per ht)
  bf16x8 bfE0 = WpV[(0 * 4 + ht0) * 64 + l];
  bf16x8 bfE1 = WpV[(0 * 4 + ht1) * 64 + l];
  float  bvE0 = bp[(0 * 4 + ht0) * 16 + c];
  float  bvE1 = bp[(0 * 4 + ht1) * 16 + c];
  bf16x8 bfO0 = WpV[(1 * 4 + ht0) * 64 + l];
  bf16x8 bfO1 = WpV[(1 * 4 + ht1) * 64 + l];
  float  bvO0 = bp[(1 * 4 + ht0) * 16 + c];
  float  bvO1 = bp[(1 * 4 + ht1) * 16 + c];

  __syncthreads();   // hs ready

  const int hoff = g << 2;

  // pipeline register sets: tmp (E/O parity x ht x as), hv (E/O, h-invariant)
  f32x4 tEA0, tEA1, tEA2, tEA3, tEB0, tEB1, tEB2, tEB3;
  f32x4 tOA0, tOA1, tOA2, tOA3, tOB0, tOB1, tOB2, tOB3;
  f32x4 hE0, hE1, hE2, hE3, hO0, hO1, hO2, hO3;

#define ISSUE_SET2(TA0, TA1, TA2, TA3, TB0, TB1, TB2, TB3, BF0, BV0, BF1, BV1)     \
  {                                                                                \
    const f32x4 cb0 = {BV0, BV0, BV0, BV0};                                        \
    const f32x4 cb1 = {BV1, BV1, BV1, BV1};                                        \
    TA0 = __builtin_amdgcn_mfma_f32_16x16x32_bf16(afr[0], BF0, cb0, 0, 0, 0);      \
    TA1 = __builtin_amdgcn_mfma_f32_16x16x32_bf16(afr[1], BF0, cb0, 0, 0, 0);      \
    TA2 = __builtin_amdgcn_mfma_f32_16x16x32_bf16(afr[2], BF0, cb0, 0, 0, 0);      \
    TA3 = __builtin_amdgcn_mfma_f32_16x16x32_bf16(afr[3], BF0, cb0, 0, 0, 0);      \
    TB0 = __builtin_amdgcn_mfma_f32_16x16x32_bf16(afr[0], BF1, cb1, 0, 0, 0);      \
    TB1 = __builtin_amdgcn_mfma_f32_16x16x32_bf16(afr[1], BF1, cb1, 0, 0, 0);      \
    TB2 = __builtin_amdgcn_mfma_f32_16x16x32_bf16(afr[2], BF1, cb1, 0, 0, 0);      \
    TB3 = __builtin_amdgcn_mfma_f32_16x16x32_bf16(afr[3], BF1, cb1, 0, 0, 0);      \
    asm volatile("" : "+v"(TA0), "+v"(TA1), "+v"(TA2), "+v"(TA3),                  \
                      "+v"(TB0), "+v"(TB1), "+v"(TB2), "+v"(TB3));                 \
  }

#define LOADHV_SET(H0, H1, H2, H3, D0)                                             \
  {                                                                                \
    H0 = *(const f32x4*)&hs[(D0) * EPF +  0 + hoff];                               \
    H1 = *(const f32x4*)&hs[(D0) * EPF + 16 + hoff];                               \
    H2 = *(const f32x4*)&hs[(D0) * EPF + 32 + hoff];                               \
    H3 = *(const f32x4*)&hs[(D0) * EPF + 48 + hoff];                               \
  }

#define CONSUME_ONE2(ACCA, ACCB, AS, TT, HH)                                       \
  {                                                                                \
    f32x2 p, hl, hh;                                                               \
    hl = __builtin_shufflevector(HH, HH, 0, 1);                                    \
    hh = __builtin_shufflevector(HH, HH, 2, 3);                                    \
    p[0] = fmaxf(TT[0], 0.f); p[1] = fmaxf(TT[1], 0.f);                            \
    asm volatile("v_pk_fma_f32 %0, %1, %2, %0" : "+v"(ACCA[AS]) : "v"(p), "v"(hl));\
    p[0] = fmaxf(TT[2], 0.f); p[1] = fmaxf(TT[3], 0.f);                            \
    asm volatile("v_pk_fma_f32 %0, %1, %2, %0" : "+v"(ACCB[AS]) : "v"(p), "v"(hh));\
  }

#define CONSUME_BOTH(TA0, TA1, TA2, TA3, TB0, TB1, TB2, TB3, H0, H1, H2, H3)       \
  CONSUME_ONE2(accA0, accB0, 0, TA0, H0) CONSUME_ONE2(accA0, accB0, 1, TA1, H1)    \
  CONSUME_ONE2(accA0, accB0, 2, TA2, H2) CONSUME_ONE2(accA0, accB0, 3, TA3, H3)    \
  CONSUME_ONE2(accA1, accB1, 0, TB0, H0) CONSUME_ONE2(accA1, accB1, 1, TB1, H1)    \
  CONSUME_ONE2(accA1, accB1, 2, TB2, H2) CONSUME_ONE2(accA1, accB1, 3, TB3, H3)

  // prologue: issue sections d0=0 (E) and d0=1 (O)
  ISSUE_SET2(tEA0, tEA1, tEA2, tEA3, tEB0, tEB1, tEB2, tEB3, bfE0, bvE0, bfE1, bvE1)
  LOADHV_SET(hE0, hE1, hE2, hE3, 0)
  bfE0 = WpV[(2 * 4 + ht0) * 64 + l];  bvE0 = bp[(2 * 4 + ht0) * 16 + c];
  bfE1 = WpV[(2 * 4 + ht1) * 64 + l];  bvE1 = bp[(2 * 4 + ht1) * 16 + c];
  ISSUE_SET2(tOA0, tOA1, tOA2, tOA3, tOB0, tOB1, tOB2, tOB3, bfO0, bvO0, bfO1, bvO1)
  LOADHV_SET(hO0, hO1, hO2, hO3, 1)
  bfO0 = WpV[(3 * 4 + ht0) * 64 + l];  bvO0 = bp[(3 * 4 + ht0) * 16 + c];
  bfO1 = WpV[(3 * 4 + ht1) * 64 + l];  bvO1 = bp[(3 * 4 + ht1) * 16 + c];

#pragma unroll 2
  for (int d0 = 2; d0 < 64; d0 += 2) {
    // consume E (d0-2), reissue E (d0)
    CONSUME_BOTH(tEA0, tEA1, tEA2, tEA3, tEB0, tEB1, tEB2, tEB3, hE0, hE1, hE2, hE3)
    ISSUE_SET2(tEA0, tEA1, tEA2, tEA3, tEB0, tEB1, tEB2, tEB3, bfE0, bvE0, bfE1, bvE1)
    LOADHV_SET(hE0, hE1, hE2, hE3, d0)
    if (d0 + 2 < 64) {
      bfE0 = WpV[((d0 + 2) * 4 + ht0) * 64 + l];  bvE0 = bp[((d0 + 2) * 4 + ht0) * 16 + c];
      bfE1 = WpV[((d0 + 2) * 4 + ht1) * 64 + l];  bvE1 = bp[((d0 + 2) * 4 + ht1) * 16 + c];
    }
    // consume O (d0-1), reissue O (d0+1)
    CONSUME_BOTH(tOA0, tOA1, tOA2, tOA3, tOB0, tOB1, tOB2, tOB3, hO0, hO1, hO2, hO3)
    ISSUE_SET2(tOA0, tOA1, tOA2, tOA3, tOB0, tOB1, tOB2, tOB3, bfO0, bvO0, bfO1, bvO1)
    LOADHV_SET(hO0, hO1, hO2, hO3, d0 + 1)
    if (d0 + 3 < 64) {
      bfO0 = WpV[((d0 + 3) * 4 + ht0) * 64 + l];  bvO0 = bp[((d0 + 3) * 4 + ht0) * 16 + c];
      bfO1 = WpV[((d0 + 3) * 4 + ht1) * 64 + l];  bvO1 = bp[((d0 + 3) * 4 + ht1) * 16 + c];
    }
  }

  // epilogue: consume last two sections (d0=62 E, d0=63 O)
  CONSUME_BOTH(tEA0, tEA1, tEA2, tEA3, tEB0, tEB1, tEB2, tEB3, hE0, hE1, hE2, hE3)
  CONSUME_BOTH(tOA0, tOA1, tOA2, tOA3, tOB0, tOB1, tOB2, tOB3, hO0, hO1, hO2, hO3)

#undef ISSUE_SET2
#undef LOADHV_SET
#undef CONSUME_ONE2
#undef CONSUME_BOTH

  // stores (bf16): per (ht, as, row): 16 lanes x 2B = 32B segments
  const int hb0 = (ht0 << 4) + c;
  const int hb1 = (ht1 << 4) + c;
#pragma unroll
  for (int as = 0; as < 4; ++as) {
    const int ebase = eblk + as * 16 + (g << 2);
    m[((ebase + 0) << 6) + hb0] = (__bf16)accA0[as][0];
    m[((ebase + 1) << 6) + hb0] = (__bf16)accA0[as][1];
    m[((ebase + 2) << 6) + hb0] = (__bf16)accB0[as][0];
    m[((ebase + 3) << 6) + hb0] = (__bf16)accB0[as][1];
    m[((ebase + 0) << 6) + hb1] = (__bf16)accA1[as][0];
    m[((ebase + 1) << 6) + hb1] = (__bf16)accA1[as][1];
    m[((ebase + 2) << 6) + hb1] = (__bf16)accB1[as][0];
    m[((ebase + 3) << 6) + hb1] = (__bf16)accB1[as][1];
  }
}

// ---- final: gather-mean per dst (CSR, bf16 m, 4-deep ILP) + relu(concat@Wn + bn) ----
__global__ __launch_bounds__(256) void final6_kernel(
    const float* __restrict__ nf, const __bf16* __restrict__ m,
    const int* __restrict__ off, const int* __restrict__ eid,
    const float* __restrict__ Wn, const float* __restrict__ bn,
    float* __restrict__ out) {
  __shared__ float wn_s[128 * 64];   // 32 KB
  __shared__ float hn_s[8 * 64];     // 2 KB
  const int t = threadIdx.x;
#pragma unroll
  for (int i = 0; i < 8; ++i)
    ((f32x4*)wn_s)[i * 256 + t] = ((const f32x4*)Wn)[i * 256 + t];

  const int w = t >> 6, h = t & 63;
  const int row0 = blockIdx.x * 8 + w * 2;

#pragma unroll
  for (int i = 0; i < 2; ++i) {
    const int d = row0 + i;
    const int lo = off[d], hi = off[d + 1];
    float a0 = 0.f, a1 = 0.f, a2 = 0.f, a3 = 0.f;
    int j = lo;
    for (; j + 4 <= hi; j += 4) {
      const int e0 = eid[j], e1 = eid[j + 1], e2 = eid[j + 2], e3 = eid[j + 3];
      a0 += (float)m[(e0 << 6) + h];
      a1 += (float)m[(e1 << 6) + h];
      a2 += (float)m[(e2 << 6) + h];
      a3 += (float)m[(e3 << 6) + h];
    }
    for (; j < hi; ++j)
      a0 += (float)m[(eid[j] << 6) + h];
    const float a = (a0 + a1) + (a2 + a3);
    hn_s[(w * 2 + i) * 64 + h] = (hi > lo) ? a * (1.f / (float)(hi - lo)) : 0.f;
  }
  __syncthreads();

  const float bv = bn[h];
  float acc[2] = {bv, bv};
#pragma unroll 4
  for (int k = 0; k < 64; ++k) {
    const float wv = wn_s[k * 64 + h];
#pragma unroll
    for (int i = 0; i < 2; ++i)
      acc[i] = fmaf(nf[(row0 + i) * 64 + k], wv, acc[i]);
  }
#pragma unroll 4
  for (int k = 0; k < 64; ++k) {
    const float wv = wn_s[(64 + k) * 64 + h];
#pragma unroll
    for (int i = 0; i < 2; ++i)
      acc[i] = fmaf(hn_s[(w * 2 + i) * 64 + k], wv, acc[i]);
  }
#pragma unroll
  for (int i = 0; i < 2; ++i)
    out[(row0 + i) * 64 + h] = fmaxf(acc[i], 0.f);
}

// ================= atomic fallback (R3, proven) =================

__global__ __launch_bounds__(256, 4) void edge_kernel(
    const float* __restrict__ nf, const float* __restrict__ ef,
    const int* __restrict__ src, const int* __restrict__ dst,
    const __bf16* __restrict__ Wp, const float* __restrict__ bp,
    float* __restrict__ msum, float* __restrict__ cnt_g) {
  __shared__ __bf16 hs[64 * EPW];
  const int t = threadIdx.x;
  const int eblk = blockIdx.x << 6;
  {
    const int el = t & 63, q = t >> 6;
    const int srow = src[eblk + el];
    const f32x4* nfr = (const f32x4*)(nf + (srow << 6) + (q << 4));
#pragma unroll
    for (int i = 0; i < 4; ++i) {
      f32x4 v = nfr[i];
      const int dbase = (q << 4) + i * 4;
      hs[(dbase + 0) * EPW + el] = (__bf16)v[0];
      hs[(dbase + 1) * EPW + el] = (__bf16)v[1];
      hs[(dbase + 2) * EPW + el] = (__bf16)v[2];
      hs[(dbase + 3) * EPW + el] = (__bf16)v[3];
    }
  }
  const int w = t >> 6, l = t & 63, c = l & 15, g = l >> 4;
  bf16x8 afr[4];
#pragma unroll
  for (int as = 0; as < 4; ++as) {
    const int e = eblk + as * 16 + c;
    const f32x4* p = (const f32x4*)(ef + (e << 5) + (g << 3));
    f32x4 v0 = p[0], v1 = p[1];
    bf16x8 a;
    a[0] = (__bf16)v0[0]; a[1] = (__bf16)v0[1]; a[2] = (__bf16)v0[2]; a[3] = (__bf16)v0[3];
    a[4] = (__bf16)v1[0]; a[5] = (__bf16)v1[1]; a[6] = (__bf16)v1[2]; a[7] = (__bf16)v1[3];
    afr[as] = a;
  }
  __syncthreads();
  f32x4 acc[4];
#pragma unroll
  for (int i = 0; i < 4; ++i) { acc[i][0]=0.f; acc[i][1]=0.f; acc[i][2]=0.f; acc[i][3]=0.f; }
  const bf16x8* WpV = (const bf16x8*)Wp;
  const f32x4 zero = {0.f, 0.f, 0.f, 0.f};
#pragma unroll 4
  for (int d0 = 0; d0 < 64; ++d0) {
    const int T = d0 * 4 + w;
    const bf16x8 bfr = WpV[T * 64 + l];
    const float bv = bp[T * 16 + c];
    const f32x4 cb = {bv, bv, bv, bv};
#pragma unroll
    for (int as = 0; as < 4; ++as) {
      const bf16x4 hv = *(const bf16x4*)&hs[d0 * EPW + as * 16 + (g << 2)];
      const f32x4 hvf = {(float)hv[0], (float)hv[1], (float)hv[2], (float)hv[3]};
      f32x4 tmp = __builtin_amdgcn_mfma_f32_16x16x32_bf16(afr[as], bfr, cb, 0, 0, 0);
      tmp = __builtin_elementwise_max(tmp, zero);
      acc[as] = tmp * hvf + acc[as];
    }
  }
#pragma unroll
  for (int as = 0; as < 4; ++as)
#pragma unroll
    for (int r = 0; r < 4; ++r) {
      const int e = eblk + as * 16 + (g << 2) + r;
      const int dd = dst[e];
      unsafeAtomicAdd(msum + (dd << 6) + (w << 4) + c, acc[as][r]);
      if (w == 0 && c == 0) unsafeAtomicAdd(cnt_g + dd, 1.0f);
    }
}

__global__ __launch_bounds__(256) void final_kernel(
    const float* __restrict__ nf, const float* __restrict__ msum,
    const float* __restrict__ cnt, const float* __restrict__ Wn,
    const float* __restrict__ bn, float* __restrict__ out) {
  __shared__ float wn_s[128 * 64];
  const int t = threadIdx.x;
#pragma unroll
  for (int i = 0; i < 8; ++i)
    ((f32x4*)wn_s)[i * 256 + t] = ((const f32x4*)Wn)[i * 256 + t];
  __syncthreads();
  const int w = t >> 6, h = t & 63;
  const int row0 = blockIdx.x * 16 + w * 4;
  const float bv = bn[h];
  float acc[4] = {bv, bv, bv, bv};
  float s[4];
#pragma unroll
  for (int i = 0; i < 4; ++i) {
    const float cv = cnt[row0 + i];
    s[i] = cv > 0.f ? 1.f / cv : 0.f;
  }
#pragma unroll 4
  for (int k = 0; k < 64; ++k) {
    const float wv = wn_s[k * 64 + h];
#pragma unroll
    for (int i = 0; i < 4; ++i) acc[i] = fmaf(nf[(row0 + i) * 64 + k], wv, acc[i]);
  }
#pragma unroll 4
  for (int k = 0; k < 64; ++k) {
    const float wv = wn_s[(64 + k) * 64 + h];
#pragma unroll
    for (int i = 0; i < 4; ++i) acc[i] = fmaf(msum[(row0 + i) * 64 + k] * s[i], wv, acc[i]);
  }
#pragma unroll
  for (int i = 0; i < 4; ++i) out[(row0 + i) * 64 + h] = fmaxf(acc[i], 0.f);
}

// ================= launcher =================

extern "C" void kernel_launch(void* const* d_in, const int* in_sizes, int n_in,
                              void* d_out, int out_size, void* d_ws, size_t ws_size,
                              hipStream_t stream) {
  const float* nf  = (const float*)d_in[0];
  const float* ef  = (const float*)d_in[1];
  const int*   src = (const int*)d_in[2];
  const int*   dst = (const int*)d_in[3];
  const float* We  = (const float*)d_in[4];
  const float* be  = (const float*)d_in[5];
  const float* Wn  = (const float*)d_in[6];
  const float* bn  = (const float*)d_in[7];
  float* out = (float*)d_out;
  char* ws = (char*)d_ws;

  const size_t MB = 16777216;  // m region bytes (layout unchanged; bf16 m uses half)
  const size_t T_OFF    = MB;
  const size_t T_CURSOR = T_OFF + 36864;
  const size_t T_CNTI   = T_CURSOR + 32768;
  const size_t T_EID    = T_CNTI + 32768;
  const size_t T_WP     = T_EID + 262144;
  const size_t T_BP     = T_WP + 262144;
  const size_t NEED     = T_BP + 16384;      // ~17.4 MB

  if (ws_size >= NEED) {
    __bf16* m      = (__bf16*)ws;
    int*    off    = (int*)(ws + T_OFF);
    int*    cursor = (int*)(ws + T_CURSOR);
    int*    cnt_i  = (int*)(ws + T_CNTI);
    int*    eid    = (int*)(ws + T_EID);
    __bf16* Wp     = (__bf16*)(ws + T_WP);
    float*  bp     = (float*)(ws + T_BP);

    prep_kernel<<<64, 256, 0, stream>>>(We, be, Wp, bp, cnt_i);
    edge12_kernel<<<E_TOT / 64, 128, 0, stream>>>(nf, ef, src, dst, Wp, bp, m, cnt_i);
    scan_kernel<<<1, 256, 0, stream>>>(cnt_i, off, cursor);
    fill_kernel<<<E_TOT / 256, 256, 0, stream>>>(dst, cursor, eid);
    final6_kernel<<<NDST / 8, 256, 0, stream>>>(nf, m, off, eid, Wn, bn, out);
  } else {
    // atomic fallback
    float* msum = (float*)ws;
    float* cnt  = (float*)(ws + 2097152);
    const size_t need = 2097152 + 32768 + 262144 + 16384;
    __bf16* Wp;
    float*  bp;
    if (ws_size >= need) {
      Wp = (__bf16*)(ws + 2097152 + 32768);
      bp = (float*)(ws + 2097152 + 32768 + 262144);
    } else {
      Wp = (__bf16*)d_out;
      bp = (float*)((char*)d_out + 262144);
    }
    hipMemsetAsync(msum, 0, 2097152 + 32768, stream);
    prep_kernel<<<64, 256, 0, stream>>>(We, be, Wp, bp, (int*)cnt);
    edge_kernel<<<E_TOT / 64, 256, 0, stream>>>(nf, ef, src, dst, Wp, bp, msum, cnt);
    final_kernel<<<NDST / 16, 256, 0, stream>>>(nf, msum, cnt, Wn, bn, out);
  }
}